// Round 2
// baseline (1338.050 us; speedup 1.0000x reference)
//
#include <hip/hip_runtime.h>
#include <math.h>

#define B_    2
#define N_    9216
#define C_    192
#define HEADS_ 6
#define HD_   32
#define T_    2304
#define MEM_  8
#define TK_   2312      // T_ + MEM_
#define MLPH_ 384
#define SCALE_ 0.17677669529663687f
#define EPS_  1e-5f

static __device__ __forceinline__ float gelu_erf(float x) {
    return 0.5f * x * (1.0f + erff(x * 0.70710678118654752f));
}

// ---------------- mean over (B,N) of x -> mean_x[192] ----------------
__global__ void k_rowpart(const float* __restrict__ x, float* __restrict__ part) {
    int j = threadIdx.x;                       // 0..191
    const float* p = x + (size_t)blockIdx.x * 128 * C_;
    float s = 0.f;
    for (int r = 0; r < 128; ++r) s += p[r * C_ + j];
    part[blockIdx.x * C_ + j] = s;
}

__global__ void k_meanfin(const float* __restrict__ part, float* __restrict__ meanx) {
    int j = threadIdx.x;
    float s = 0.f;
    for (int i = 0; i < 144; ++i) s += part[i * C_ + j];
    meanx[j] = s * (1.0f / 18432.0f);
}

// ------------- 2x2 avgpool + LN + K/V projections (16 tokens/block) -------------
__global__ void k_kvproj(const float* __restrict__ x,
                         const float* __restrict__ lnw, const float* __restrict__ lnb,
                         const float* __restrict__ wk, const float* __restrict__ bk,
                         const float* __restrict__ wv, const float* __restrict__ bv,
                         float* __restrict__ kcat, float* __restrict__ vcat) {
    __shared__ float A[16][193];
    __shared__ float mu[16], rs[16];
    int j = threadIdx.x;                       // 0..191
    int bb   = blockIdx.x / 144;
    int tile = blockIdx.x % 144;
    int t0 = tile * 16;
    int h2 = t0 / 48, w20 = t0 % 48;           // 48%16==0 -> tile stays in one pooled row
    for (int r = 0; r < 16; ++r) {
        int w2 = w20 + r;
        size_t base = ((size_t)bb * N_ + (2 * h2) * 96 + 2 * w2) * C_;
        float p00 = x[base + j];
        float p01 = x[base + C_ + j];
        float p10 = x[base + 96 * C_ + j];
        float p11 = x[base + 96 * C_ + C_ + j];
        A[r][j] = 0.25f * (p00 + p01 + p10 + p11);
    }
    __syncthreads();
    if (j < 16) {
        float s = 0.f, ss = 0.f;
        for (int k = 0; k < C_; ++k) { float a = A[j][k]; s += a; ss += a * a; }
        float m = s * (1.0f / C_);
        float var = ss * (1.0f / C_) - m * m;
        mu[j] = m; rs[j] = rsqrtf(var + EPS_);
    }
    __syncthreads();
    float lw = lnw[j], lb = lnb[j];
    for (int r = 0; r < 16; ++r) A[r][j] = (A[r][j] - mu[r]) * rs[r] * lw + lb;
    __syncthreads();
    float ak[16], av[16];
#pragma unroll
    for (int r = 0; r < 16; ++r) { ak[r] = 0.f; av[r] = 0.f; }
    for (int k = 0; k < C_; ++k) {
        float wkv = wk[k * C_ + j];
        float wvv = wv[k * C_ + j];
#pragma unroll
        for (int r = 0; r < 16; ++r) { float a = A[r][k]; ak[r] += a * wkv; av[r] += a * wvv; }
    }
    float bkj = bk[j], bvj = bv[j];
    for (int r = 0; r < 16; ++r) {
        size_t row = (size_t)bb * TK_ + t0 + r;
        kcat[row * C_ + j] = ak[r] + bkj;
        vcat[row * C_ + j] = av[r] + bvj;
    }
}

// ------------- EMA memory rows: bin means of k/v, write rows T..T+7 -------------
__global__ void k_mem(const float* __restrict__ meanx,
                      float* __restrict__ kcat, float* __restrict__ vcat) {
    int m = blockIdx.x, j = threadIdx.x;       // m: 0..7, j: 0..191
    float sk = 0.f, sv = 0.f;
    for (int bb = 0; bb < 2; ++bb)
        for (int t = 0; t < 288; ++t) {
            size_t row = (size_t)bb * TK_ + m * 288 + t;
            sk += kcat[row * C_ + j];
            sv += vcat[row * C_ + j];
        }
    float kb = sk * (1.0f / 576.0f), vb = sv * (1.0f / 576.0f);
    float mk = 0.99f * meanx[j] + 0.01f * kb;
    float mv = 0.01f * vb;
    for (int bb = 0; bb < 2; ++bb) {
        size_t row = (size_t)bb * TK_ + T_ + m;
        kcat[row * C_ + j] = mk;
        vcat[row * C_ + j] = mv;
    }
}

// ------------- LN(x) @ wq + bq (16 tokens/block) -------------
__global__ void k_qproj(const float* __restrict__ x,
                        const float* __restrict__ lnw, const float* __restrict__ lnb,
                        const float* __restrict__ wq, const float* __restrict__ bq,
                        float* __restrict__ q) {
    __shared__ float A[16][193];
    __shared__ float mu[16], rs[16];
    int j = threadIdx.x;
    size_t row0 = (size_t)blockIdx.x * 16;
    for (int r = 0; r < 16; ++r) A[r][j] = x[(row0 + r) * C_ + j];
    __syncthreads();
    if (j < 16) {
        float s = 0.f, ss = 0.f;
        for (int k = 0; k < C_; ++k) { float a = A[j][k]; s += a; ss += a * a; }
        float m = s * (1.0f / C_);
        float var = ss * (1.0f / C_) - m * m;
        mu[j] = m; rs[j] = rsqrtf(var + EPS_);
    }
    __syncthreads();
    float lw = lnw[j], lb = lnb[j];
    for (int r = 0; r < 16; ++r) A[r][j] = (A[r][j] - mu[r]) * rs[r] * lw + lb;
    __syncthreads();
    float acc[16];
#pragma unroll
    for (int r = 0; r < 16; ++r) acc[r] = 0.f;
    for (int k = 0; k < C_; ++k) {
        float w = wq[k * C_ + j];
#pragma unroll
        for (int r = 0; r < 16; ++r) acc[r] += A[r][k] * w;
    }
    float bj = bq[j];
    for (int r = 0; r < 16; ++r) q[(row0 + r) * C_ + j] = acc[r] + bj;
}

// ------------- attention: 1 thread = 1 query row, K/V tiled in LDS -------------
__global__ __launch_bounds__(256) void k_attn(const float* __restrict__ q,
                                              const float* __restrict__ kcat,
                                              const float* __restrict__ vcat,
                                              float* __restrict__ ao) {
    __shared__ float kt[64][32];
    __shared__ float vt[64][32];
    int tid = threadIdx.x;
    int bb = blockIdx.z, h = blockIdx.y;
    int row = blockIdx.x * 256 + tid;          // 0..9215
    float qreg[32];
    {
        const float4* qp = reinterpret_cast<const float4*>(
            q + ((size_t)bb * N_ + row) * C_ + h * HD_);
#pragma unroll
        for (int c = 0; c < 8; ++c) {
            float4 v = qp[c];
            qreg[4 * c + 0] = v.x * SCALE_; qreg[4 * c + 1] = v.y * SCALE_;
            qreg[4 * c + 2] = v.z * SCALE_; qreg[4 * c + 3] = v.w * SCALE_;
        }
    }
    float acc[32];
#pragma unroll
    for (int d = 0; d < 32; ++d) acc[d] = 0.f;
    float mmax = -3.4e38f, lsum = 0.f;

    for (int t0 = 0; t0 < TK_; t0 += 64) {
        int nk = min(64, TK_ - t0);
        __syncthreads();
        for (int e = tid; e < nk * 32; e += 256) {
            int kk = e >> 5, d = e & 31;
            size_t src = ((size_t)bb * TK_ + t0 + kk) * C_ + h * HD_ + d;
            kt[kk][d] = kcat[src];
            vt[kk][d] = vcat[src];
        }
        __syncthreads();
        for (int kk = 0; kk < nk; ++kk) {
            const float4* k4 = reinterpret_cast<const float4*>(&kt[kk][0]);
            float s = 0.f;
#pragma unroll
            for (int c = 0; c < 8; ++c) {
                float4 kv = k4[c];
                s += qreg[4 * c + 0] * kv.x + qreg[4 * c + 1] * kv.y +
                     qreg[4 * c + 2] * kv.z + qreg[4 * c + 3] * kv.w;
            }
            const float4* v4 = reinterpret_cast<const float4*>(&vt[kk][0]);
            if (s <= mmax) {
                float p = __expf(s - mmax);
                lsum += p;
#pragma unroll
                for (int c = 0; c < 8; ++c) {
                    float4 vv = v4[c];
                    acc[4 * c + 0] += p * vv.x; acc[4 * c + 1] += p * vv.y;
                    acc[4 * c + 2] += p * vv.z; acc[4 * c + 3] += p * vv.w;
                }
            } else {
                float cf = __expf(mmax - s);
                mmax = s;
                lsum = lsum * cf + 1.f;
#pragma unroll
                for (int c = 0; c < 8; ++c) {
                    float4 vv = v4[c];
                    acc[4 * c + 0] = acc[4 * c + 0] * cf + vv.x;
                    acc[4 * c + 1] = acc[4 * c + 1] * cf + vv.y;
                    acc[4 * c + 2] = acc[4 * c + 2] * cf + vv.z;
                    acc[4 * c + 3] = acc[4 * c + 3] * cf + vv.w;
                }
            }
        }
    }
    float invl = 1.f / lsum;
    float4* op = reinterpret_cast<float4*>(ao + ((size_t)bb * N_ + row) * C_ + h * HD_);
#pragma unroll
    for (int c = 0; c < 8; ++c) {
        float4 o;
        o.x = acc[4 * c + 0] * invl; o.y = acc[4 * c + 1] * invl;
        o.z = acc[4 * c + 2] * invl; o.w = acc[4 * c + 3] * invl;
        op[c] = o;
    }
}

// ------------- out@wo+bo -> LN -> MLP(GELU) -> +residual -> f32 out -------------
__global__ void k_post(const float* __restrict__ ao,
                       const float* __restrict__ wo, const float* __restrict__ bo,
                       const float* __restrict__ ln2w, const float* __restrict__ ln2b,
                       const float* __restrict__ w1, const float* __restrict__ b1,
                       const float* __restrict__ w2, const float* __restrict__ b2,
                       float* __restrict__ out) {
    __shared__ float A[16][193];
    __shared__ float H[16][385];
    __shared__ float mu[16], rs[16];
    int j = threadIdx.x;                       // 0..191
    size_t row0 = (size_t)blockIdx.x * 16;

    for (int r = 0; r < 16; ++r) A[r][j] = ao[(row0 + r) * C_ + j];
    __syncthreads();

    float o[16];
#pragma unroll
    for (int r = 0; r < 16; ++r) o[r] = 0.f;
    for (int k = 0; k < C_; ++k) {
        float w = wo[k * C_ + j];
#pragma unroll
        for (int r = 0; r < 16; ++r) o[r] += A[r][k] * w;
    }
    float boj = bo[j];
#pragma unroll
    for (int r = 0; r < 16; ++r) o[r] += boj;
    __syncthreads();                            // all reads of A done
    for (int r = 0; r < 16; ++r) A[r][j] = o[r];
    __syncthreads();

    if (j < 16) {
        float s = 0.f, ss = 0.f;
        for (int k = 0; k < C_; ++k) { float a = A[j][k]; s += a; ss += a * a; }
        float m = s * (1.0f / C_);
        float var = ss * (1.0f / C_) - m * m;
        mu[j] = m; rs[j] = rsqrtf(var + EPS_);
    }
    __syncthreads();
    float lw = ln2w[j], lb = ln2b[j];
    for (int r = 0; r < 16; ++r) A[r][j] = (A[r][j] - mu[r]) * rs[r] * lw + lb;
    __syncthreads();

    float g0[16], g1[16];
#pragma unroll
    for (int r = 0; r < 16; ++r) { g0[r] = 0.f; g1[r] = 0.f; }
    for (int k = 0; k < C_; ++k) {
        float wa = w1[k * MLPH_ + j];
        float wb = w1[k * MLPH_ + j + 192];
#pragma unroll
        for (int r = 0; r < 16; ++r) { float a = A[r][k]; g0[r] += a * wa; g1[r] += a * wb; }
    }
    float b1a = b1[j], b1b = b1[j + 192];
#pragma unroll
    for (int r = 0; r < 16; ++r) {
        g0[r] = gelu_erf(g0[r] + b1a);
        g1[r] = gelu_erf(g1[r] + b1b);
    }
    for (int r = 0; r < 16; ++r) { H[r][j] = g0[r]; H[r][j + 192] = g1[r]; }
    __syncthreads();

    float f[16];
#pragma unroll
    for (int r = 0; r < 16; ++r) f[r] = 0.f;
    for (int k = 0; k < MLPH_; ++k) {
        float w = w2[k * C_ + j];
#pragma unroll
        for (int r = 0; r < 16; ++r) f[r] += H[r][k] * w;
    }
    float b2j = b2[j];
    for (int r = 0; r < 16; ++r)
        out[(row0 + r) * C_ + j] = o[r] + f[r] + b2j;
}

extern "C" void kernel_launch(void* const* d_in, const int* in_sizes, int n_in,
                              void* d_out, int out_size, void* d_ws, size_t ws_size,
                              hipStream_t stream) {
    const float* x    = (const float*)d_in[0];
    const float* lnqw = (const float*)d_in[1];
    const float* lnqb = (const float*)d_in[2];
    const float* lnkw = (const float*)d_in[3];
    const float* lnkb = (const float*)d_in[4];
    const float* wq   = (const float*)d_in[5];
    const float* bq   = (const float*)d_in[6];
    const float* wk   = (const float*)d_in[7];
    const float* bk   = (const float*)d_in[8];
    const float* wv   = (const float*)d_in[9];
    const float* bv   = (const float*)d_in[10];
    const float* wo   = (const float*)d_in[11];
    const float* bo   = (const float*)d_in[12];
    const float* ln2w = (const float*)d_in[13];
    const float* ln2b = (const float*)d_in[14];
    const float* w1   = (const float*)d_in[15];
    const float* b1   = (const float*)d_in[16];
    const float* w2   = (const float*)d_in[17];
    const float* b2   = (const float*)d_in[18];

    float* ws    = (float*)d_ws;
    float* q     = ws;                               // B*N*C
    float* kcat  = q    + (size_t)B_ * N_ * C_;      // B*TK*C
    float* vcat  = kcat + (size_t)B_ * TK_ * C_;     // B*TK*C
    float* ao    = vcat + (size_t)B_ * TK_ * C_;     // B*N*C
    float* part  = ao   + (size_t)B_ * N_ * C_;      // 144*C
    float* meanx = part + 144 * C_;                  // C

    hipLaunchKernelGGL(k_rowpart, dim3(144), dim3(192), 0, stream, x, part);
    hipLaunchKernelGGL(k_meanfin, dim3(1), dim3(192), 0, stream, part, meanx);
    hipLaunchKernelGGL(k_kvproj, dim3(288), dim3(192), 0, stream,
                       x, lnkw, lnkb, wk, bk, wv, bv, kcat, vcat);
    hipLaunchKernelGGL(k_mem, dim3(8), dim3(192), 0, stream, meanx, kcat, vcat);
    hipLaunchKernelGGL(k_qproj, dim3(1152), dim3(192), 0, stream,
                       x, lnqw, lnqb, wq, bq, q);
    hipLaunchKernelGGL(k_attn, dim3(36, 6, 2), dim3(256), 0, stream, q, kcat, vcat, ao);
    hipLaunchKernelGGL(k_post, dim3(1152), dim3(192), 0, stream,
                       ao, wo, bo, ln2w, ln2b, w1, b1, w2, b2, (float*)d_out);
}

// Round 3
// 541.259 us; speedup vs baseline: 2.4721x; 2.4721x over previous
//
#include <hip/hip_runtime.h>
#include <hip/hip_bf16.h>
#include <math.h>

#define B_    2
#define N_    9216
#define C_    192
#define HEADS_ 6
#define HD_   32
#define T_    2304
#define MEM_  8
#define TK_   2312      // T_ + MEM_
#define TKP_  2336      // padded to multiple of 32
#define MLPH_ 384
#define SCALE_ 0.17677669529663687f
#define EPS_  1e-5f

typedef __bf16 v8bf __attribute__((ext_vector_type(8)));
typedef __bf16 v4bf __attribute__((ext_vector_type(4)));
typedef float  v4f  __attribute__((ext_vector_type(4)));

#define MFMA16(a, b, c) __builtin_amdgcn_mfma_f32_16x16x32_bf16((a), (b), (c), 0, 0, 0)

static __device__ __forceinline__ float gelu_erf(float x) {
    return 0.5f * x * (1.0f + erff(x * 0.70710678118654752f));
}

// ---------------- mean over (B,N) of x -> mean_x[192] ----------------
__global__ void k_rowpart(const float* __restrict__ x, float* __restrict__ part) {
    int j = threadIdx.x;                       // 0..191
    const float* p = x + (size_t)blockIdx.x * 128 * C_;
    float s = 0.f;
    for (int r = 0; r < 128; ++r) s += p[r * C_ + j];
    part[blockIdx.x * C_ + j] = s;
}

__global__ void k_meanfin(const float* __restrict__ part, float* __restrict__ meanx) {
    int j = threadIdx.x;
    float s = 0.f;
    for (int i = 0; i < 144; ++i) s += part[i * C_ + j];
    meanx[j] = s * (1.0f / 18432.0f);
}

// ------------- 2x2 avgpool + LN + K/V projections (16 tokens/block), bf16 out -------------
__global__ void k_kvproj(const float* __restrict__ x,
                         const float* __restrict__ lnw, const float* __restrict__ lnb,
                         const float* __restrict__ wk, const float* __restrict__ bk,
                         const float* __restrict__ wv, const float* __restrict__ bv,
                         __bf16* __restrict__ kcat, __bf16* __restrict__ vcat) {
    __shared__ float A[16][193];
    __shared__ float mu[16], rs[16];
    int j = threadIdx.x;                       // 0..191
    int bb   = blockIdx.x / 144;
    int tile = blockIdx.x % 144;
    int t0 = tile * 16;
    int h2 = t0 / 48, w20 = t0 % 48;
    for (int r = 0; r < 16; ++r) {
        int w2 = w20 + r;
        size_t base = ((size_t)bb * N_ + (2 * h2) * 96 + 2 * w2) * C_;
        float p00 = x[base + j];
        float p01 = x[base + C_ + j];
        float p10 = x[base + 96 * C_ + j];
        float p11 = x[base + 96 * C_ + C_ + j];
        A[r][j] = 0.25f * (p00 + p01 + p10 + p11);
    }
    __syncthreads();
    if (j < 16) {
        float s = 0.f, ss = 0.f;
        for (int k = 0; k < C_; ++k) { float a = A[j][k]; s += a; ss += a * a; }
        float m = s * (1.0f / C_);
        float var = ss * (1.0f / C_) - m * m;
        mu[j] = m; rs[j] = rsqrtf(var + EPS_);
    }
    __syncthreads();
    float lw = lnw[j], lb = lnb[j];
    for (int r = 0; r < 16; ++r) A[r][j] = (A[r][j] - mu[r]) * rs[r] * lw + lb;
    __syncthreads();
    float ak[16], av[16];
#pragma unroll
    for (int r = 0; r < 16; ++r) { ak[r] = 0.f; av[r] = 0.f; }
    for (int k = 0; k < C_; ++k) {
        float wkv = wk[k * C_ + j];
        float wvv = wv[k * C_ + j];
#pragma unroll
        for (int r = 0; r < 16; ++r) { float a = A[r][k]; ak[r] += a * wkv; av[r] += a * wvv; }
    }
    float bkj = bk[j], bvj = bv[j];
    for (int r = 0; r < 16; ++r) {
        size_t row = (size_t)bb * TKP_ + t0 + r;
        kcat[row * C_ + j] = (__bf16)(ak[r] + bkj);
        vcat[row * C_ + j] = (__bf16)(av[r] + bvj);
    }
}

// ------- EMA memory rows (blocks 0..7) + zero pad rows (blocks 8..31) -------
__global__ void k_mem(const float* __restrict__ meanx,
                      __bf16* __restrict__ kcat, __bf16* __restrict__ vcat) {
    int m = blockIdx.x, j = threadIdx.x;       // j: 0..191
    if (m < 8) {
        float sk = 0.f, sv = 0.f;
        for (int bb = 0; bb < 2; ++bb)
            for (int t = 0; t < 288; ++t) {
                size_t row = (size_t)bb * TKP_ + m * 288 + t;
                sk += (float)kcat[row * C_ + j];
                sv += (float)vcat[row * C_ + j];
            }
        float kb = sk * (1.0f / 576.0f), vb = sv * (1.0f / 576.0f);
        float mk = 0.99f * meanx[j] + 0.01f * kb;
        float mv = 0.01f * vb;
        for (int bb = 0; bb < 2; ++bb) {
            size_t row = (size_t)bb * TKP_ + T_ + m;
            kcat[row * C_ + j] = (__bf16)mk;
            vcat[row * C_ + j] = (__bf16)mv;
        }
    } else {
        int r = TK_ + (m - 8);                 // 2312..2335
        for (int bb = 0; bb < 2; ++bb) {
            size_t row = (size_t)bb * TKP_ + r;
            kcat[row * C_ + j] = (__bf16)0.f;
            vcat[row * C_ + j] = (__bf16)0.f;
        }
    }
}

// ------------- LN(x) @ wq + bq, *SCALE, bf16 out (16 tokens/block) -------------
__global__ void k_qproj(const float* __restrict__ x,
                        const float* __restrict__ lnw, const float* __restrict__ lnb,
                        const float* __restrict__ wq, const float* __restrict__ bq,
                        __bf16* __restrict__ q) {
    __shared__ float A[16][193];
    __shared__ float mu[16], rs[16];
    int j = threadIdx.x;
    size_t row0 = (size_t)blockIdx.x * 16;
    for (int r = 0; r < 16; ++r) A[r][j] = x[(row0 + r) * C_ + j];
    __syncthreads();
    if (j < 16) {
        float s = 0.f, ss = 0.f;
        for (int k = 0; k < C_; ++k) { float a = A[j][k]; s += a; ss += a * a; }
        float m = s * (1.0f / C_);
        float var = ss * (1.0f / C_) - m * m;
        mu[j] = m; rs[j] = rsqrtf(var + EPS_);
    }
    __syncthreads();
    float lw = lnw[j], lb = lnb[j];
    for (int r = 0; r < 16; ++r) A[r][j] = (A[r][j] - mu[r]) * rs[r] * lw + lb;
    __syncthreads();
    float acc[16];
#pragma unroll
    for (int r = 0; r < 16; ++r) acc[r] = 0.f;
    for (int k = 0; k < C_; ++k) {
        float w = wq[k * C_ + j];
#pragma unroll
        for (int r = 0; r < 16; ++r) acc[r] += A[r][k] * w;
    }
    float bj = bq[j];
    for (int r = 0; r < 16; ++r)
        q[(row0 + r) * C_ + j] = (__bf16)((acc[r] + bj) * SCALE_);
}

// ------------- MFMA attention: 4 waves x 16 queries, KVBLK=32 -------------
// Swapped QK^T: S^T = mfma(K_frag, Q_frag) -> lane holds S^T[4 keys][q=lane&15].
// PV: O^T = mfma(V^T_frag, P^T_frag) -> col = q = lane&15 (in-lane rescale).
__global__ __launch_bounds__(256) void k_attn(const __bf16* __restrict__ q,
                                              const __bf16* __restrict__ kc,
                                              const __bf16* __restrict__ vc,
                                              float* __restrict__ ao) {
    __shared__ __bf16 vt[32 * 32];             // XOR-swizzled V^T tile (d-major)
    __shared__ __bf16 pl[4][16][40];           // per-wave P[q][kk], stride 40
    int tid  = threadIdx.x;
    int w    = tid >> 6;
    int lane = tid & 63;
    int g    = lane >> 4;                      // 0..3 (k-slice group)
    int qi   = lane & 15;                      // query col / d row
    int bb = blockIdx.z, h = blockIdx.y;
    int qt = blockIdx.x * 64 + w * 16;

    // Q fragment (B operand): Q[qi][g*8 + j], scale pre-folded
    v8bf qf = *(const v8bf*)(q + ((size_t)bb * N_ + qt + qi) * C_ + h * HD_ + g * 8);

    v4f olo = {0.f, 0.f, 0.f, 0.f};
    v4f ohi = {0.f, 0.f, 0.f, 0.f};
    float m = -1e30f, lsum = 0.f;

    int skey = tid >> 3;                       // 0..31
    int sd0  = (tid & 7) * 4;                  // 0,4,..,28
    const __bf16* vbase = vc + (size_t)bb * TKP_ * C_ + h * HD_ + sd0;
    const __bf16* kbase = kc + ((size_t)bb * TKP_ + qi) * C_ + h * HD_ + g * 8;

    for (int kv0 = 0; kv0 < TKP_; kv0 += 32) {
        __syncthreads();                       // prev-iter vt reads done
        // stage V^T tile: vt[d][key], byte ^= (d&7)<<4
        {
            v4bf vv = *(const v4bf*)(vbase + (size_t)(kv0 + skey) * C_);
#pragma unroll
            for (int i = 0; i < 4; ++i) {
                int d = sd0 + i;
                int byte = (d * 64 + skey * 2) ^ ((d & 7) << 4);
                *(__bf16*)((char*)vt + byte) = vv[i];
            }
        }
        // K fragments direct from global (L2-hot)
        v8bf kf0 = *(const v8bf*)(kbase + (size_t)kv0 * C_);
        v8bf kf1 = *(const v8bf*)(kbase + (size_t)(kv0 + 16) * C_);
        v4f z = {0.f, 0.f, 0.f, 0.f};
        v4f s0 = MFMA16(kf0, qf, z);           // S^T keys kv0+0..15
        v4f s1 = MFMA16(kf1, qf, z);           // S^T keys kv0+16..31

        if (kv0 + 32 > TK_) {                  // tail mask (pad keys)
#pragma unroll
            for (int r = 0; r < 4; ++r) {
                if (kv0 + g * 4 + r >= TK_)      s0[r] = -1e30f;
                if (kv0 + 16 + g * 4 + r >= TK_) s1[r] = -1e30f;
            }
        }

        // online softmax for q = qi (replicated across 4 g-lanes)
        float mx = fmaxf(fmaxf(fmaxf(s0[0], s0[1]), fmaxf(s0[2], s0[3])),
                         fmaxf(fmaxf(s1[0], s1[1]), fmaxf(s1[2], s1[3])));
        mx = fmaxf(mx, __shfl_xor(mx, 16));
        mx = fmaxf(mx, __shfl_xor(mx, 32));
        float mn = fmaxf(m, mx);
        float cf = __expf(m - mn);
        float p[8], ps = 0.f;
#pragma unroll
        for (int r = 0; r < 4; ++r) { p[r]     = __expf(s0[r] - mn); ps += p[r]; }
#pragma unroll
        for (int r = 0; r < 4; ++r) { p[4 + r] = __expf(s1[r] - mn); ps += p[4 + r]; }
        ps += __shfl_xor(ps, 16);
        ps += __shfl_xor(ps, 32);
        lsum = lsum * cf + ps;
        m = mn;
#pragma unroll
        for (int r = 0; r < 4; ++r) { olo[r] *= cf; ohi[r] *= cf; }

        // P -> bf16 -> LDS (per-wave tile), then PV
        v4bf p0, p1;
#pragma unroll
        for (int r = 0; r < 4; ++r) { p0[r] = (__bf16)p[r]; p1[r] = (__bf16)p[4 + r]; }
        *(v4bf*)&pl[w][qi][g * 4]      = p0;
        *(v4bf*)&pl[w][qi][16 + g * 4] = p1;

        __syncthreads();                       // vt staged (also orders pl within wave)

        v8bf pb = *(const v8bf*)&pl[w][qi][g * 8];
        int blo = (qi * 64 + g * 16) ^ ((qi & 7) << 4);
        int bhi = ((qi + 16) * 64 + g * 16) ^ (((qi + 16) & 7) << 4);
        v8bf va0 = *(const v8bf*)((char*)vt + blo);
        v8bf va1 = *(const v8bf*)((char*)vt + bhi);
        olo = MFMA16(va0, pb, olo);
        ohi = MFMA16(va1, pb, ohi);
    }

    float inv = 1.f / lsum;
    float* orow = ao + ((size_t)bb * N_ + qt + qi) * C_ + h * HD_;
    v4f flo, fhi;
#pragma unroll
    for (int r = 0; r < 4; ++r) { flo[r] = olo[r] * inv; fhi[r] = ohi[r] * inv; }
    *(v4f*)(orow + g * 4)      = flo;
    *(v4f*)(orow + 16 + g * 4) = fhi;
}

// ------------- out@wo+bo -> LN -> MLP(GELU) -> +residual -> f32 out -------------
__global__ void k_post(const float* __restrict__ ao,
                       const float* __restrict__ wo, const float* __restrict__ bo,
                       const float* __restrict__ ln2w, const float* __restrict__ ln2b,
                       const float* __restrict__ w1, const float* __restrict__ b1,
                       const float* __restrict__ w2, const float* __restrict__ b2,
                       float* __restrict__ out) {
    __shared__ float A[16][193];
    __shared__ float H[16][385];
    __shared__ float mu[16], rs[16];
    int j = threadIdx.x;                       // 0..191
    size_t row0 = (size_t)blockIdx.x * 16;

    for (int r = 0; r < 16; ++r) A[r][j] = ao[(row0 + r) * C_ + j];
    __syncthreads();

    float o[16];
#pragma unroll
    for (int r = 0; r < 16; ++r) o[r] = 0.f;
    for (int k = 0; k < C_; ++k) {
        float w = wo[k * C_ + j];
#pragma unroll
        for (int r = 0; r < 16; ++r) o[r] += A[r][k] * w;
    }
    float boj = bo[j];
#pragma unroll
    for (int r = 0; r < 16; ++r) o[r] += boj;
    __syncthreads();
    for (int r = 0; r < 16; ++r) A[r][j] = o[r];
    __syncthreads();

    if (j < 16) {
        float s = 0.f, ss = 0.f;
        for (int k = 0; k < C_; ++k) { float a = A[j][k]; s += a; ss += a * a; }
        float m = s * (1.0f / C_);
        float var = ss * (1.0f / C_) - m * m;
        mu[j] = m; rs[j] = rsqrtf(var + EPS_);
    }
    __syncthreads();
    float lw = ln2w[j], lb = ln2b[j];
    for (int r = 0; r < 16; ++r) A[r][j] = (A[r][j] - mu[r]) * rs[r] * lw + lb;
    __syncthreads();

    float g0[16], g1[16];
#pragma unroll
    for (int r = 0; r < 16; ++r) { g0[r] = 0.f; g1[r] = 0.f; }
    for (int k = 0; k < C_; ++k) {
        float wa = w1[k * MLPH_ + j];
        float wb = w1[k * MLPH_ + j + 192];
#pragma unroll
        for (int r = 0; r < 16; ++r) { float a = A[r][k]; g0[r] += a * wa; g1[r] += a * wb; }
    }
    float b1a = b1[j], b1b = b1[j + 192];
#pragma unroll
    for (int r = 0; r < 16; ++r) {
        g0[r] = gelu_erf(g0[r] + b1a);
        g1[r] = gelu_erf(g1[r] + b1b);
    }
    for (int r = 0; r < 16; ++r) { H[r][j] = g0[r]; H[r][j + 192] = g1[r]; }
    __syncthreads();

    float f[16];
#pragma unroll
    for (int r = 0; r < 16; ++r) f[r] = 0.f;
    for (int k = 0; k < MLPH_; ++k) {
        float w = w2[k * C_ + j];
#pragma unroll
        for (int r = 0; r < 16; ++r) f[r] += H[r][k] * w;
    }
    float b2j = b2[j];
    for (int r = 0; r < 16; ++r)
        out[(row0 + r) * C_ + j] = o[r] + f[r] + b2j;
}

extern "C" void kernel_launch(void* const* d_in, const int* in_sizes, int n_in,
                              void* d_out, int out_size, void* d_ws, size_t ws_size,
                              hipStream_t stream) {
    const float* x    = (const float*)d_in[0];
    const float* lnqw = (const float*)d_in[1];
    const float* lnqb = (const float*)d_in[2];
    const float* lnkw = (const float*)d_in[3];
    const float* lnkb = (const float*)d_in[4];
    const float* wq   = (const float*)d_in[5];
    const float* bq   = (const float*)d_in[6];
    const float* wk   = (const float*)d_in[7];
    const float* bk   = (const float*)d_in[8];
    const float* wv   = (const float*)d_in[9];
    const float* bv   = (const float*)d_in[10];
    const float* wo   = (const float*)d_in[11];
    const float* bo   = (const float*)d_in[12];
    const float* ln2w = (const float*)d_in[13];
    const float* ln2b = (const float*)d_in[14];
    const float* w1   = (const float*)d_in[15];
    const float* b1   = (const float*)d_in[16];
    const float* w2   = (const float*)d_in[17];
    const float* b2   = (const float*)d_in[18];

    char* w0 = (char*)d_ws;
    const size_t QB  = (size_t)B_ * N_ * C_ * 2;       // 7,077,888
    const size_t KVB = (size_t)B_ * TKP_ * C_ * 2;     // 1,794,048
    __bf16* qb  = (__bf16*)(w0);
    __bf16* kcb = (__bf16*)(w0 + QB);
    __bf16* vcb = (__bf16*)(w0 + QB + KVB);
    float*  ao  = (float*) (w0 + QB + 2 * KVB);
    float*  part  = (float*)(w0 + QB + 2 * KVB + (size_t)B_ * N_ * C_ * 4);
    float*  meanx = part + 144 * C_;

    hipLaunchKernelGGL(k_rowpart, dim3(144), dim3(192), 0, stream, x, part);
    hipLaunchKernelGGL(k_meanfin, dim3(1), dim3(192), 0, stream, part, meanx);
    hipLaunchKernelGGL(k_kvproj, dim3(288), dim3(192), 0, stream,
                       x, lnkw, lnkb, wk, bk, wv, bv, kcb, vcb);
    hipLaunchKernelGGL(k_mem, dim3(32), dim3(192), 0, stream, meanx, kcb, vcb);
    hipLaunchKernelGGL(k_qproj, dim3(1152), dim3(192), 0, stream,
                       x, lnqw, lnqb, wq, bq, qb);
    hipLaunchKernelGGL(k_attn, dim3(144, 6, 2), dim3(256), 0, stream, qb, kcb, vcb, ao);
    hipLaunchKernelGGL(k_post, dim3(1152), dim3(192), 0, stream,
                       ao, wo, bo, ln2w, ln2b, w1, b1, w2, b2, (float*)d_out);
}

// Round 4
// 283.318 us; speedup vs baseline: 4.7228x; 1.9104x over previous
//
#include <hip/hip_runtime.h>
#include <hip/hip_bf16.h>
#include <math.h>

#define B_    2
#define N_    9216
#define C_    192
#define HD_   32
#define T_    2304
#define MEM_  8
#define TK_   2312      // T_ + MEM_
#define TKP_  2336      // padded to multiple of 32
#define MLPH_ 384
#define SCALE_ 0.17677669529663687f
#define EPS_  1e-5f

typedef __bf16 v8bf __attribute__((ext_vector_type(8)));
typedef __bf16 v4bf __attribute__((ext_vector_type(4)));
typedef float  v4f  __attribute__((ext_vector_type(4)));

#define MFMA16(a, b, c) __builtin_amdgcn_mfma_f32_16x16x32_bf16((a), (b), (c), 0, 0, 0)

static __device__ __forceinline__ float gelu_erf(float x) {
    return 0.5f * x * (1.0f + erff(x * 0.70710678118654752f));
}

// ---------------- mean over (B,N) of x -> mean_x[192] ----------------
__global__ void k_rowpart(const float* __restrict__ x, float* __restrict__ part) {
    int j = threadIdx.x;
    const float* p = x + (size_t)blockIdx.x * 128 * C_;
    float s = 0.f;
    for (int r = 0; r < 128; ++r) s += p[r * C_ + j];
    part[blockIdx.x * C_ + j] = s;
}

__global__ void k_meanfin(const float* __restrict__ part, float* __restrict__ meanx) {
    int j = threadIdx.x;
    float s = 0.f;
    for (int i = 0; i < 144; ++i) s += part[i * C_ + j];
    meanx[j] = s * (1.0f / 18432.0f);
}

// ---------------- weight transpose+convert to bf16 ----------------
__global__ void k_prep(const float* __restrict__ wq, const float* __restrict__ wk,
                       const float* __restrict__ wv, const float* __restrict__ wo,
                       const float* __restrict__ w1, const float* __restrict__ w2,
                       __bf16* __restrict__ wqT, __bf16* __restrict__ wkT,
                       __bf16* __restrict__ wvT, __bf16* __restrict__ woT,
                       __bf16* __restrict__ w1T, __bf16* __restrict__ w2T) {
    int idx = blockIdx.x * 256 + threadIdx.x;
    if (idx < 4 * 36864) {
        int m = idx / 36864, e = idx % 36864;
        int n = e / 192, k = e % 192;
        const float* src = (m == 0) ? wq : (m == 1) ? wk : (m == 2) ? wv : wo;
        __bf16* dst = (m == 0) ? wqT : (m == 1) ? wkT : (m == 2) ? wvT : woT;
        dst[n * 192 + k] = (__bf16)src[k * 192 + n];
    } else if (idx < 4 * 36864 + 73728) {
        int e = idx - 4 * 36864;
        int n = e / 192, k = e % 192;          // w1T[384][192]
        w1T[n * 192 + k] = (__bf16)w1[k * 384 + n];
    } else if (idx < 4 * 36864 + 2 * 73728) {
        int e = idx - 4 * 36864 - 73728;
        int n = e / 384, k = e % 384;          // w2T[192][384]
        w2T[n * 384 + k] = (__bf16)w2[k * 192 + n];
    }
}

// ---------------- MFMA q-projection: LN(x) @ wq + bq, *SCALE ----------------
__global__ __launch_bounds__(256) void k_qproj(const float* __restrict__ x,
        const float* __restrict__ lnw, const float* __restrict__ lnb,
        const __bf16* __restrict__ wqT, const float* __restrict__ bq,
        __bf16* __restrict__ q) {
    __shared__ float  Of[32][196];
    __shared__ __bf16 Abf[32][200];
    __shared__ float  mu_s[32], rs_s[32];
    int tid = threadIdx.x;
    int w = tid >> 6, lane = tid & 63, qi = lane & 15, g = lane >> 4;
    size_t row0 = (size_t)blockIdx.x * 32;

    for (int e = tid; e < 32 * 48; e += 256) {
        int r = e / 48, c4 = e % 48;
        *(float4*)&Of[r][c4 * 4] = *(const float4*)(x + (row0 + r) * C_ + c4 * 4);
    }
    __syncthreads();
    {
        int r = tid >> 3, part = tid & 7;
        float s = 0.f, ss = 0.f;
        for (int i = 0; i < 24; ++i) { float a = Of[r][part * 24 + i]; s += a; ss += a * a; }
        s += __shfl_xor(s, 1); ss += __shfl_xor(ss, 1);
        s += __shfl_xor(s, 2); ss += __shfl_xor(ss, 2);
        s += __shfl_xor(s, 4); ss += __shfl_xor(ss, 4);
        if (part == 0) {
            float m = s * (1.f / C_);
            float var = ss * (1.f / C_) - m * m;
            mu_s[r] = m; rs_s[r] = rsqrtf(var + EPS_);
        }
    }
    __syncthreads();
    {
        int r = tid >> 3, part = tid & 7;
        float m = mu_s[r], rv = rs_s[r];
        for (int i = 0; i < 24; ++i) {
            int c = part * 24 + i;
            Abf[r][c] = (__bf16)((Of[r][c] - m) * rv * lnw[c] + lnb[c]);
        }
    }
    __syncthreads();

    v4f acc[2][3];
#pragma unroll
    for (int m = 0; m < 2; ++m)
#pragma unroll
        for (int n = 0; n < 3; ++n) acc[m][n] = (v4f){0.f, 0.f, 0.f, 0.f};
#pragma unroll
    for (int kk = 0; kk < 6; ++kk) {
        v8bf a0 = *(const v8bf*)&Abf[qi][kk * 32 + g * 8];
        v8bf a1 = *(const v8bf*)&Abf[16 + qi][kk * 32 + g * 8];
#pragma unroll
        for (int n = 0; n < 3; ++n) {
            v8bf bfr = *(const v8bf*)(wqT + (size_t)(w * 48 + n * 16 + qi) * C_ + kk * 32 + g * 8);
            acc[0][n] = MFMA16(a0, bfr, acc[0][n]);
            acc[1][n] = MFMA16(a1, bfr, acc[1][n]);
        }
    }
#pragma unroll
    for (int n = 0; n < 3; ++n) {
        int col = w * 48 + n * 16 + qi;
        float bb = bq[col];
#pragma unroll
        for (int m = 0; m < 2; ++m)
#pragma unroll
            for (int r = 0; r < 4; ++r)
                q[(row0 + m * 16 + g * 4 + r) * C_ + col] = (__bf16)((acc[m][n][r] + bb) * SCALE_);
    }
}

// ------- MFMA kv-projection: 2x2 avgpool -> LN -> @wk,@wv (+bias), bf16 out -------
__global__ __launch_bounds__(256) void k_kvproj(const float* __restrict__ x,
        const float* __restrict__ lnw, const float* __restrict__ lnb,
        const __bf16* __restrict__ wkT, const float* __restrict__ bk,
        const __bf16* __restrict__ wvT, const float* __restrict__ bv,
        __bf16* __restrict__ kcat, __bf16* __restrict__ vcat) {
    __shared__ float  Of[32][196];
    __shared__ __bf16 Abf[32][200];
    __shared__ float  mu_s[32], rs_s[32];
    int tid = threadIdx.x;
    int w = tid >> 6, lane = tid & 63, qi = lane & 15, g = lane >> 4;
    int p0 = blockIdx.x * 32;                  // pooled row base; 2304%32==0 -> one batch
    int bbb = p0 / T_, tbase = p0 % T_;

    for (int e = tid; e < 32 * 48; e += 256) {
        int r = e / 48, c4 = e % 48;
        int t = tbase + r;
        int h2 = t / 48, w2c = t % 48;
        const float* s0 = x + ((size_t)bbb * N_ + (size_t)(2 * h2) * 96 + 2 * w2c) * C_ + c4 * 4;
        float4 u0 = *(const float4*)(s0);
        float4 u1 = *(const float4*)(s0 + C_);
        float4 u2 = *(const float4*)(s0 + 96 * C_);
        float4 u3 = *(const float4*)(s0 + 96 * C_ + C_);
        float4 a;
        a.x = 0.25f * (u0.x + u1.x + u2.x + u3.x);
        a.y = 0.25f * (u0.y + u1.y + u2.y + u3.y);
        a.z = 0.25f * (u0.z + u1.z + u2.z + u3.z);
        a.w = 0.25f * (u0.w + u1.w + u2.w + u3.w);
        *(float4*)&Of[r][c4 * 4] = a;
    }
    __syncthreads();
    {
        int r = tid >> 3, part = tid & 7;
        float s = 0.f, ss = 0.f;
        for (int i = 0; i < 24; ++i) { float a = Of[r][part * 24 + i]; s += a; ss += a * a; }
        s += __shfl_xor(s, 1); ss += __shfl_xor(ss, 1);
        s += __shfl_xor(s, 2); ss += __shfl_xor(ss, 2);
        s += __shfl_xor(s, 4); ss += __shfl_xor(ss, 4);
        if (part == 0) {
            float m = s * (1.f / C_);
            float var = ss * (1.f / C_) - m * m;
            mu_s[r] = m; rs_s[r] = rsqrtf(var + EPS_);
        }
    }
    __syncthreads();
    {
        int r = tid >> 3, part = tid & 7;
        float m = mu_s[r], rv = rs_s[r];
        for (int i = 0; i < 24; ++i) {
            int c = part * 24 + i;
            Abf[r][c] = (__bf16)((Of[r][c] - m) * rv * lnw[c] + lnb[c]);
        }
    }
    __syncthreads();

    v4f ak[2][3], av[2][3];
#pragma unroll
    for (int m = 0; m < 2; ++m)
#pragma unroll
        for (int n = 0; n < 3; ++n) { ak[m][n] = (v4f){0.f,0.f,0.f,0.f}; av[m][n] = (v4f){0.f,0.f,0.f,0.f}; }
#pragma unroll
    for (int kk = 0; kk < 6; ++kk) {
        v8bf a0 = *(const v8bf*)&Abf[qi][kk * 32 + g * 8];
        v8bf a1 = *(const v8bf*)&Abf[16 + qi][kk * 32 + g * 8];
#pragma unroll
        for (int n = 0; n < 3; ++n) {
            int col = w * 48 + n * 16 + qi;
            v8bf bk8 = *(const v8bf*)(wkT + (size_t)col * C_ + kk * 32 + g * 8);
            v8bf bv8 = *(const v8bf*)(wvT + (size_t)col * C_ + kk * 32 + g * 8);
            ak[0][n] = MFMA16(a0, bk8, ak[0][n]);
            ak[1][n] = MFMA16(a1, bk8, ak[1][n]);
            av[0][n] = MFMA16(a0, bv8, av[0][n]);
            av[1][n] = MFMA16(a1, bv8, av[1][n]);
        }
    }
#pragma unroll
    for (int n = 0; n < 3; ++n) {
        int col = w * 48 + n * 16 + qi;
        float bkc = bk[col], bvc = bv[col];
#pragma unroll
        for (int m = 0; m < 2; ++m)
#pragma unroll
            for (int r = 0; r < 4; ++r) {
                int t = tbase + m * 16 + g * 4 + r;
                size_t row = (size_t)bbb * TKP_ + t;
                kcat[row * C_ + col] = (__bf16)(ak[m][n][r] + bkc);
                vcat[row * C_ + col] = (__bf16)(av[m][n][r] + bvc);
            }
    }
}

// ------- EMA memory rows (blocks 0..7) + zero pad rows (blocks 8..31) -------
__global__ void k_mem(const float* __restrict__ meanx,
                      __bf16* __restrict__ kcat, __bf16* __restrict__ vcat) {
    int m = blockIdx.x, j = threadIdx.x;
    if (m < 8) {
        float sk = 0.f, sv = 0.f;
        for (int bb = 0; bb < 2; ++bb)
            for (int t = 0; t < 288; ++t) {
                size_t row = (size_t)bb * TKP_ + m * 288 + t;
                sk += (float)kcat[row * C_ + j];
                sv += (float)vcat[row * C_ + j];
            }
        float kb = sk * (1.0f / 576.0f), vb = sv * (1.0f / 576.0f);
        float mk = 0.99f * meanx[j] + 0.01f * kb;
        float mv = 0.01f * vb;
        for (int bb = 0; bb < 2; ++bb) {
            size_t row = (size_t)bb * TKP_ + T_ + m;
            kcat[row * C_ + j] = (__bf16)mk;
            vcat[row * C_ + j] = (__bf16)mv;
        }
    } else {
        int r = TK_ + (m - 8);
        for (int bb = 0; bb < 2; ++bb) {
            size_t row = (size_t)bb * TKP_ + r;
            kcat[row * C_ + j] = (__bf16)0.f;
            vcat[row * C_ + j] = (__bf16)0.f;
        }
    }
}

// ------------- MFMA attention: 4 waves x 16 queries, KVBLK=32 -------------
__global__ __launch_bounds__(256) void k_attn(const __bf16* __restrict__ q,
                                              const __bf16* __restrict__ kc,
                                              const __bf16* __restrict__ vc,
                                              float* __restrict__ ao) {
    __shared__ __bf16 vt[32 * 32];
    __shared__ __bf16 pl[4][16][40];
    int tid  = threadIdx.x;
    int w    = tid >> 6;
    int lane = tid & 63;
    int g    = lane >> 4;
    int qi   = lane & 15;
    int bb = blockIdx.z, h = blockIdx.y;
    int qt = blockIdx.x * 64 + w * 16;

    v8bf qf = *(const v8bf*)(q + ((size_t)bb * N_ + qt + qi) * C_ + h * HD_ + g * 8);

    v4f olo = {0.f, 0.f, 0.f, 0.f};
    v4f ohi = {0.f, 0.f, 0.f, 0.f};
    float m = -1e30f, lsum = 0.f;

    int skey = tid >> 3;
    int sd0  = (tid & 7) * 4;
    const __bf16* vbase = vc + (size_t)bb * TKP_ * C_ + h * HD_ + sd0;
    const __bf16* kbase = kc + ((size_t)bb * TKP_ + qi) * C_ + h * HD_ + g * 8;

    for (int kv0 = 0; kv0 < TKP_; kv0 += 32) {
        __syncthreads();
        {
            v4bf vv = *(const v4bf*)(vbase + (size_t)(kv0 + skey) * C_);
#pragma unroll
            for (int i = 0; i < 4; ++i) {
                int d = sd0 + i;
                int byte = (d * 64 + skey * 2) ^ ((d & 7) << 4);
                *(__bf16*)((char*)vt + byte) = vv[i];
            }
        }
        v8bf kf0 = *(const v8bf*)(kbase + (size_t)kv0 * C_);
        v8bf kf1 = *(const v8bf*)(kbase + (size_t)(kv0 + 16) * C_);
        v4f z = {0.f, 0.f, 0.f, 0.f};
        v4f s0 = MFMA16(kf0, qf, z);
        v4f s1 = MFMA16(kf1, qf, z);

        if (kv0 + 32 > TK_) {
#pragma unroll
            for (int r = 0; r < 4; ++r) {
                if (kv0 + g * 4 + r >= TK_)      s0[r] = -1e30f;
                if (kv0 + 16 + g * 4 + r >= TK_) s1[r] = -1e30f;
            }
        }

        float mx = fmaxf(fmaxf(fmaxf(s0[0], s0[1]), fmaxf(s0[2], s0[3])),
                         fmaxf(fmaxf(s1[0], s1[1]), fmaxf(s1[2], s1[3])));
        mx = fmaxf(mx, __shfl_xor(mx, 16));
        mx = fmaxf(mx, __shfl_xor(mx, 32));
        float mn = fmaxf(m, mx);
        float cf = __expf(m - mn);
        float p[8], ps = 0.f;
#pragma unroll
        for (int r = 0; r < 4; ++r) { p[r]     = __expf(s0[r] - mn); ps += p[r]; }
#pragma unroll
        for (int r = 0; r < 4; ++r) { p[4 + r] = __expf(s1[r] - mn); ps += p[4 + r]; }
        ps += __shfl_xor(ps, 16);
        ps += __shfl_xor(ps, 32);
        lsum = lsum * cf + ps;
        m = mn;
#pragma unroll
        for (int r = 0; r < 4; ++r) { olo[r] *= cf; ohi[r] *= cf; }

        v4bf p0, p1;
#pragma unroll
        for (int r = 0; r < 4; ++r) { p0[r] = (__bf16)p[r]; p1[r] = (__bf16)p[4 + r]; }
        *(v4bf*)&pl[w][qi][g * 4]      = p0;
        *(v4bf*)&pl[w][qi][16 + g * 4] = p1;

        __syncthreads();

        v8bf pb = *(const v8bf*)&pl[w][qi][g * 8];
        int blo = (qi * 64 + g * 16) ^ ((qi & 7) << 4);
        int bhi = ((qi + 16) * 64 + g * 16) ^ (((qi + 16) & 7) << 4);
        v8bf va0 = *(const v8bf*)((char*)vt + blo);
        v8bf va1 = *(const v8bf*)((char*)vt + bhi);
        olo = MFMA16(va0, pb, olo);
        ohi = MFMA16(va1, pb, ohi);
    }

    float inv = 1.f / lsum;
    float* orow = ao + ((size_t)bb * N_ + qt + qi) * C_ + h * HD_;
    v4f flo, fhi;
#pragma unroll
    for (int r = 0; r < 4; ++r) { flo[r] = olo[r] * inv; fhi[r] = ohi[r] * inv; }
    *(v4f*)(orow + g * 4)      = flo;
    *(v4f*)(orow + 16 + g * 4) = fhi;
}

// ---- MFMA post: ao@wo+bo -> LN -> MLP(GELU exact) -> +residual -> f32 out ----
__global__ __launch_bounds__(256) void k_post(const float* __restrict__ ao,
        const __bf16* __restrict__ woT, const float* __restrict__ bo,
        const float* __restrict__ ln2w, const float* __restrict__ ln2b,
        const __bf16* __restrict__ w1T, const float* __restrict__ b1,
        const __bf16* __restrict__ w2T, const float* __restrict__ b2,
        float* __restrict__ out) {
    __shared__ __bf16 Abf[32][200];
    __shared__ float  Of[32][196];
    __shared__ __bf16 H[32][392];
    __shared__ float  mu_s[32], rs_s[32];
    int tid = threadIdx.x;
    int w = tid >> 6, lane = tid & 63, qi = lane & 15, g = lane >> 4;
    size_t row0 = (size_t)blockIdx.x * 32;

    // stage 0: ao -> bf16 A tile
    for (int e = tid; e < 32 * 48; e += 256) {
        int r = e / 48, c4 = e % 48;
        float4 v = *(const float4*)(ao + (row0 + r) * C_ + c4 * 4);
        v4bf p; p[0] = (__bf16)v.x; p[1] = (__bf16)v.y; p[2] = (__bf16)v.z; p[3] = (__bf16)v.w;
        *(v4bf*)&Abf[r][c4 * 4] = p;
    }
    __syncthreads();

    // GEMM1: o = A @ wo + bo (keep in regs for residual; also Of for LN)
    v4f acc1[2][3];
#pragma unroll
    for (int m = 0; m < 2; ++m)
#pragma unroll
        for (int n = 0; n < 3; ++n) acc1[m][n] = (v4f){0.f,0.f,0.f,0.f};
#pragma unroll
    for (int kk = 0; kk < 6; ++kk) {
        v8bf a0 = *(const v8bf*)&Abf[qi][kk * 32 + g * 8];
        v8bf a1 = *(const v8bf*)&Abf[16 + qi][kk * 32 + g * 8];
#pragma unroll
        for (int n = 0; n < 3; ++n) {
            v8bf bfr = *(const v8bf*)(woT + (size_t)(w * 48 + n * 16 + qi) * C_ + kk * 32 + g * 8);
            acc1[0][n] = MFMA16(a0, bfr, acc1[0][n]);
            acc1[1][n] = MFMA16(a1, bfr, acc1[1][n]);
        }
    }
#pragma unroll
    for (int n = 0; n < 3; ++n) {
        int col = w * 48 + n * 16 + qi;
        float bb = bo[col];
#pragma unroll
        for (int m = 0; m < 2; ++m)
#pragma unroll
            for (int r = 0; r < 4; ++r) {
                acc1[m][n][r] += bb;
                Of[m * 16 + g * 4 + r][col] = acc1[m][n][r];
            }
    }
    __syncthreads();

    // LN
    {
        int r = tid >> 3, part = tid & 7;
        float s = 0.f, ss = 0.f;
        for (int i = 0; i < 24; ++i) { float a = Of[r][part * 24 + i]; s += a; ss += a * a; }
        s += __shfl_xor(s, 1); ss += __shfl_xor(ss, 1);
        s += __shfl_xor(s, 2); ss += __shfl_xor(ss, 2);
        s += __shfl_xor(s, 4); ss += __shfl_xor(ss, 4);
        if (part == 0) {
            float mm = s * (1.f / C_);
            float var = ss * (1.f / C_) - mm * mm;
            mu_s[r] = mm; rs_s[r] = rsqrtf(var + EPS_);
        }
    }
    __syncthreads();
    {
        int r = tid >> 3, part = tid & 7;
        float mm = mu_s[r], rv = rs_s[r];
        for (int i = 0; i < 24; ++i) {
            int c = part * 24 + i;
            Abf[r][c] = (__bf16)((Of[r][c] - mm) * rv * ln2w[c] + ln2b[c]);
        }
    }
    __syncthreads();

    // GEMM2: g = h @ w1 + b1, GELU, -> H
    v4f acc2[2][6];
#pragma unroll
    for (int m = 0; m < 2; ++m)
#pragma unroll
        for (int n = 0; n < 6; ++n) acc2[m][n] = (v4f){0.f,0.f,0.f,0.f};
#pragma unroll
    for (int kk = 0; kk < 6; ++kk) {
        v8bf a0 = *(const v8bf*)&Abf[qi][kk * 32 + g * 8];
        v8bf a1 = *(const v8bf*)&Abf[16 + qi][kk * 32 + g * 8];
#pragma unroll
        for (int n = 0; n < 6; ++n) {
            v8bf bfr = *(const v8bf*)(w1T + (size_t)(w * 96 + n * 16 + qi) * C_ + kk * 32 + g * 8);
            acc2[0][n] = MFMA16(a0, bfr, acc2[0][n]);
            acc2[1][n] = MFMA16(a1, bfr, acc2[1][n]);
        }
    }
#pragma unroll
    for (int n = 0; n < 6; ++n) {
        int col = w * 96 + n * 16 + qi;
        float bb = b1[col];
#pragma unroll
        for (int m = 0; m < 2; ++m)
#pragma unroll
            for (int r = 0; r < 4; ++r)
                H[m * 16 + g * 4 + r][col] = (__bf16)gelu_erf(acc2[m][n][r] + bb);
    }
    __syncthreads();

    // GEMM3: f = g @ w2 + b2; out = o + f
    v4f acc3[2][3];
#pragma unroll
    for (int m = 0; m < 2; ++m)
#pragma unroll
        for (int n = 0; n < 3; ++n) acc3[m][n] = (v4f){0.f,0.f,0.f,0.f};
#pragma unroll
    for (int kk = 0; kk < 12; ++kk) {
        v8bf a0 = *(const v8bf*)&H[qi][kk * 32 + g * 8];
        v8bf a1 = *(const v8bf*)&H[16 + qi][kk * 32 + g * 8];
#pragma unroll
        for (int n = 0; n < 3; ++n) {
            v8bf bfr = *(const v8bf*)(w2T + (size_t)(w * 48 + n * 16 + qi) * MLPH_ + kk * 32 + g * 8);
            acc3[0][n] = MFMA16(a0, bfr, acc3[0][n]);
            acc3[1][n] = MFMA16(a1, bfr, acc3[1][n]);
        }
    }
#pragma unroll
    for (int n = 0; n < 3; ++n) {
        int col = w * 48 + n * 16 + qi;
        float bb = b2[col];
#pragma unroll
        for (int m = 0; m < 2; ++m)
#pragma unroll
            for (int r = 0; r < 4; ++r)
                out[(row0 + m * 16 + g * 4 + r) * C_ + col] = acc1[m][n][r] + acc3[m][n][r] + bb;
    }
}

extern "C" void kernel_launch(void* const* d_in, const int* in_sizes, int n_in,
                              void* d_out, int out_size, void* d_ws, size_t ws_size,
                              hipStream_t stream) {
    const float* x    = (const float*)d_in[0];
    const float* lnqw = (const float*)d_in[1];
    const float* lnqb = (const float*)d_in[2];
    const float* lnkw = (const float*)d_in[3];
    const float* lnkb = (const float*)d_in[4];
    const float* wq   = (const float*)d_in[5];
    const float* bq   = (const float*)d_in[6];
    const float* wk   = (const float*)d_in[7];
    const float* bk   = (const float*)d_in[8];
    const float* wv   = (const float*)d_in[9];
    const float* bv   = (const float*)d_in[10];
    const float* wo   = (const float*)d_in[11];
    const float* bo   = (const float*)d_in[12];
    const float* ln2w = (const float*)d_in[13];
    const float* ln2b = (const float*)d_in[14];
    const float* w1   = (const float*)d_in[15];
    const float* b1   = (const float*)d_in[16];
    const float* w2   = (const float*)d_in[17];
    const float* b2   = (const float*)d_in[18];

    char* w0 = (char*)d_ws;
    const size_t QB  = (size_t)B_ * N_ * C_ * 2;       // 7,077,888
    const size_t KVB = (size_t)B_ * TKP_ * C_ * 2;     // 1,794,048
    const size_t AOB = (size_t)B_ * N_ * C_ * 4;       // 14,155,776
    __bf16* qb  = (__bf16*)(w0);
    __bf16* kcb = (__bf16*)(w0 + QB);
    __bf16* vcb = (__bf16*)(w0 + QB + KVB);
    float*  ao  = (float*) (w0 + QB + 2 * KVB);
    float*  part  = (float*)(w0 + QB + 2 * KVB + AOB);
    float*  meanx = part + 144 * C_;
    char* wbase = (char*)(meanx + 192 + 32);           // keep 16B-aligned region
    wbase = (char*)(((uintptr_t)wbase + 255) & ~(uintptr_t)255);
    __bf16* wqT = (__bf16*)(wbase);
    __bf16* wkT = wqT + 36864;
    __bf16* wvT = wkT + 36864;
    __bf16* woT = wvT + 36864;
    __bf16* w1T = woT + 36864;
    __bf16* w2T = w1T + 73728;

    hipLaunchKernelGGL(k_prep, dim3(1152), dim3(256), 0, stream,
                       wq, wk, wv, wo, w1, w2, wqT, wkT, wvT, woT, w1T, w2T);
    hipLaunchKernelGGL(k_rowpart, dim3(144), dim3(192), 0, stream, x, part);
    hipLaunchKernelGGL(k_meanfin, dim3(1), dim3(192), 0, stream, part, meanx);
    hipLaunchKernelGGL(k_kvproj, dim3(144), dim3(256), 0, stream,
                       x, lnkw, lnkb, wkT, bk, wvT, bv, kcb, vcb);
    hipLaunchKernelGGL(k_mem, dim3(32), dim3(192), 0, stream, meanx, kcb, vcb);
    hipLaunchKernelGGL(k_qproj, dim3(576), dim3(256), 0, stream,
                       x, lnqw, lnqb, wqT, bq, qb);
    hipLaunchKernelGGL(k_attn, dim3(144, 6, 2), dim3(256), 0, stream, qb, kcb, vcb, ao);
    hipLaunchKernelGGL(k_post, dim3(576), dim3(256), 0, stream,
                       ao, woT, bo, ln2w, ln2b, w1T, b1, w2T, b2, (float*)d_out);
}